// Round 4
// baseline (1239.687 us; speedup 1.0000x reference)
//
#include <hip/hip_runtime.h>

// Problem constants (fixed by the reference).
constexpr int Nn  = 4096;     // nodes
constexpr int Ee  = 40960;    // edges
constexpr int ND  = 16;       // NODE_DIM
constexpr int Mm  = 64;       // M
constexpr int HD  = 32;       // head dim

#define DI __device__ __forceinline__

DI float silu_f(float x) { return x / (1.f + __expf(-x)); }
DI unsigned short bf16r(float f) {           // round-to-nearest-even bf16
    unsigned u = __float_as_uint(f);
    return (unsigned short)((u + 0x7FFFu + ((u >> 16) & 1u)) >> 16);
}
DI float bf16f(unsigned short h) { return __uint_as_float(((unsigned)h) << 16); }

// ---------------------------------------------------------------- zero fill (replaces hipMemsetAsync for graph-capture safety)
__global__ void k_zero(float* __restrict__ p, int n) {
    int i = blockIdx.x * 256 + threadIdx.x;
    if (i < n) p[i] = 0.f;
}

// ---------------------------------------------------------------- cutoff
__global__ void k_cutoff(const float* __restrict__ len, float* __restrict__ cut) {
    int e = blockIdx.x * 256 + threadIdx.x;
    if (e >= Ee) return;
    float x  = len[e] * 0.2f;           // r / R_MAX
    float x2 = x * x, x4 = x2 * x2, x6 = x4 * x2;
    float c  = 1.f - 28.f * x6 + 48.f * x6 * x - 21.f * x4 * x4;
    cut[e] = (x < 1.f) ? c : 0.f;
}

// ---------------------------------------------------------------- QK[l][a][m][m'] = sum_d Wq[l,a,m*32+d]*Wk[l,m',m*32+d]
__global__ void k_qk(const float* __restrict__ Wq, const float* __restrict__ Wk,
                     float* __restrict__ QK) {
    int idx = blockIdx.x * 256 + threadIdx.x;      // 2*16*64*64 = 131072
    int mp = idx & 63;
    int m  = (idx >> 6) & 63;
    int a  = (idx >> 12) & 15;
    int l  = idx >> 16;
    const float* q = Wq + ((size_t)(l * ND + a)) * 2048 + m * HD;
    const float* k = Wk + ((size_t)(l * Mm + mp)) * 2048 + m * HD;
    float acc = 0.f;
#pragma unroll
    for (int d = 0; d < HD; ++d) acc += q[d] * k[d];
    QK[idx] = acc;
}

// ---------------------------------------------------------------- permute W_ls[0] rows: Bp[2m+p][k] = Wls[p*64+m][k]
__global__ void k_permB(const float* __restrict__ Wls, float* __restrict__ Bp) {
    int idx = blockIdx.x * 256 + threadIdx.x;      // 128*64 = 8192
    int k = idx & 63, row = idx >> 6;              // row = 2m+p
    int m = row >> 1, pp = row & 1;
    Bp[row * 64 + k] = Wls[pp * 4096 + m * 64 + k];
}

// ---------------------------------------------------------------- QWh[n][g][m] (bf16 x4) = sum_a na[n,a]*QK4[a][m][g]
__global__ void k_qw(const float* __restrict__ na, const float* __restrict__ QK,
                     ushort4* __restrict__ QWh) {
    int n = blockIdx.x >> 2;
    int g = ((blockIdx.x & 3) << 2) + (threadIdx.x >> 6);
    int m = threadIdx.x & 63;
    const float4* QK4 = (const float4*)QK;
    const float* nar = na + n * ND;
    float4 acc = {0.f, 0.f, 0.f, 0.f};
#pragma unroll
    for (int a = 0; a < ND; ++a) {
        float w = nar[a];
        float4 q = QK4[(a * Mm + m) * 16 + g];
        acc.x += w * q.x; acc.y += w * q.y; acc.z += w * q.z; acc.w += w * q.w;
    }
    ushort4 o;
    o.x = bf16r(acc.x); o.y = bf16r(acc.y); o.z = bf16r(acc.z); o.w = bf16r(acc.w);
    QWh[((size_t)n * 16 + g) * 64 + m] = o;
}

// ---------------------------------------------------------------- A2: emb, attn, env atomics (wts is 192-wide for both layers)
__global__ void k_A2(const float* __restrict__ wts, const float* __restrict__ ang,
                     const float* __restrict__ cut, const int* __restrict__ ctr,
                     const ushort4* __restrict__ QWh,
                     float* __restrict__ env_s, float* __restrict__ env_v) {
    __shared__ float xs[256];
    int wid = threadIdx.x >> 6, m = threadIdx.x & 63;
    int e = blockIdx.x * 4 + wid;
    int c = ctr[e];
    float cute = cut[e];
    float4 sh = ((const float4*)ang)[e];   // sh.x = sh0, (y,z,w) = sh1
    const float* w = wts + (size_t)e * 192;
    float2 we = ((const float2*)w)[m];     // w_env[m,0], w_env[m,1]
    float wg = w[128 + m];                 // w_gate[m]
    float es_ = we.x * sh.x;
    float ev0 = we.y * sh.y, ev1 = we.y * sh.z, ev2 = we.y * sh.w;
    xs[threadIdx.x] = es_ * wg;
    __syncthreads();
    const float4* xv = (const float4*)(xs + wid * 64);
    const ushort4* qrow = QWh + (size_t)c * 1024;    // 16 groups * 64 m
    float logit = 0.f;
#pragma unroll
    for (int g = 0; g < 16; ++g) {
        ushort4 q = qrow[g * 64 + m];
        float4 x = xv[g];
        logit += bf16f(q.x) * x.x + bf16f(q.y) * x.y + bf16f(q.z) * x.z + bf16f(q.w) * x.w;
    }
    float attn = 1.f / (1.f + __expf(-logit * 0.2f));   // sigmoid(logit/ISQRTD)
    float ga = attn * cute * 0.2f;                      // fold 1/ENV_NORM
    atomicAdd(&env_s[(size_t)c * 64 + m], es_ * ga);
    atomicAdd(&env_v[(size_t)c * 192 + m],       ev0 * ga);
    atomicAdd(&env_v[(size_t)c * 192 + 64 + m],  ev1 * ga);
    atomicAdd(&env_v[(size_t)c * 192 + 128 + m], ev2 * ga);
}

// ---------------------------------------------------------------- scalars -> sc_mp [e][2m+p]
__global__ void k_C_s(const float* __restrict__ fs, const float* __restrict__ fv,
                      const float* __restrict__ es_t, const float* __restrict__ ev_t,
                      const int* __restrict__ ctr, float* __restrict__ sc_mp) {
    int wid = threadIdx.x >> 6, m = threadIdx.x & 63;
    int e = blockIdx.x * 4 + wid;
    int c = ctr[e];
    float es  = es_t[(size_t)c * 64 + m];
    float ev0 = ev_t[(size_t)c * 192 + m];
    float ev1 = ev_t[(size_t)c * 192 + 64 + m];
    float ev2 = ev_t[(size_t)c * 192 + 128 + m];
    float f  = fs[(size_t)e * 64 + m];
    float g0 = fv[(size_t)e * 192 + m];
    float g1 = fv[(size_t)e * 192 + 64 + m];
    float g2 = fv[(size_t)e * 192 + 128 + m];
    float2 sp;
    sp.x = f * es;
    sp.y = (g0 * ev0 + g1 * ev1 + g2 * ev2) * 0.5773502691896258f;   // 1/sqrt(3)
    ((float2*)sc_mp)[(size_t)e * 64 + m] = sp;
}

// ---------------------------------------------------------------- vectors, one component plane P -> vec [e][p*64+m]
template <int P>
__global__ void k_C_v(const float* __restrict__ fs, const float* __restrict__ fv,
                      const float* __restrict__ es_t, const float* __restrict__ ev_t,
                      const int* __restrict__ ctr, float* __restrict__ vec) {
    constexpr int Pb = (P + 1) % 3, Pc = (P + 2) % 3;
    int wid = threadIdx.x >> 6, m = threadIdx.x & 63;
    int e = blockIdx.x * 4 + wid;
    int c = ctr[e];
    float es  = es_t[(size_t)c * 64 + m];
    float evP = ev_t[(size_t)c * 192 + P  * 64 + m];
    float evB = ev_t[(size_t)c * 192 + Pb * 64 + m];
    float evC = ev_t[(size_t)c * 192 + Pc * 64 + m];
    float f   = fs[(size_t)e * 64 + m];
    float gP  = fv[(size_t)e * 192 + P  * 64 + m];
    float gB  = fv[(size_t)e * 192 + Pb * 64 + m];
    float gC  = fv[(size_t)e * 192 + Pc * 64 + m];
    constexpr float is2 = 0.7071067811865475f;
    vec[(size_t)e * 192 + m]       = f * evP;                      // v1
    vec[(size_t)e * 192 + 64 + m]  = gP * es;                      // v2
    vec[(size_t)e * 192 + 128 + m] = (gB * evC - gC * evB) * is2;  // v3 (cross)
}

// ---------------------------------------------------------------- generic tiled fp32 GEMM, 64x64 tile, K-chunks of 16
// modeA: 0 = A[row*lda+k]; 1 = concat128(A|A2); 2 = two-body gather (K=40)
// modeE: 0 = C=acc*scale; 1 = silu*cut; 2 = blend latent; 3 = acc*scale*gate; 4 = l0 feat split (fs/fv)
__global__ __launch_bounds__(256) void k_gemm(
    const float* __restrict__ A, int lda, const float* __restrict__ A2,
    const int* __restrict__ ctr, const int* __restrict__ ngh,
    const float* __restrict__ naw, const float* __restrict__ er,
    const float* __restrict__ B, int ldb, int K,
    float* __restrict__ C, int ldc, int cstride, float scale,
    const float* __restrict__ cut, const float* __restrict__ oldlat,
    const float* __restrict__ alphap, const float* __restrict__ gate,
    const float* __restrict__ ang, float* __restrict__ fsP, float* __restrict__ fvP,
    int modeA, int modeE) {
    __shared__ float a_s[16][72];
    __shared__ float b_s[16][64];
    int t = threadIdx.x;
    int row0 = blockIdx.x * 64;
    int j0 = blockIdx.y * 64;
    int tx = t & 15, ty = t >> 4;
    int ar = t & 63, akq = t >> 6;
    int bj = (t & 15) * 4, bk = t >> 4;
    float acc[4][4] = {};
    int nchunks = (K + 15) >> 4;
    for (int ch = 0; ch < nchunks; ++ch) {
        int k0 = ch * 16;
        { // A tile -> a_s[k][row] (transposed)
            int row = row0 + ar;
            int k = k0 + akq * 4;
            float4 v;
            if (modeA == 0) {
                v = *(const float4*)(A + (size_t)row * lda + k);   // K multiple of 16
            } else if (modeA == 1) {
                const float* src = (k < 128) ? (A + (size_t)row * 128 + k)
                                             : (A2 + (size_t)row * 128 + (k - 128));
                v = *(const float4*)src;
            } else {
                float tmp[4];
#pragma unroll
                for (int i = 0; i < 4; ++i) {
                    int kk = k + i; float val = 0.f;
                    if (kk < 16)      val = naw[(size_t)ctr[row] * 16 + kk];
                    else if (kk < 32) val = naw[(size_t)ngh[row] * 16 + (kk - 16)];
                    else if (kk < 40) val = er[(size_t)row * 8 + (kk - 32)];
                    tmp[i] = val;
                }
                v.x = tmp[0]; v.y = tmp[1]; v.z = tmp[2]; v.w = tmp[3];
            }
            a_s[akq * 4 + 0][ar] = v.x;
            a_s[akq * 4 + 1][ar] = v.y;
            a_s[akq * 4 + 2][ar] = v.z;
            a_s[akq * 4 + 3][ar] = v.w;
        }
        { // B tile
            int k = k0 + bk;
            float4 v = {0.f, 0.f, 0.f, 0.f};
            if (k < K) v = *(const float4*)(B + (size_t)k * ldb + j0 + bj);
            *(float4*)&b_s[bk][bj] = v;
        }
        __syncthreads();
#pragma unroll
        for (int k = 0; k < 16; ++k) {
            float4 a4 = *(const float4*)&a_s[k][ty * 4];
            float4 b4 = *(const float4*)&b_s[k][tx * 4];
            acc[0][0] += a4.x * b4.x; acc[0][1] += a4.x * b4.y; acc[0][2] += a4.x * b4.z; acc[0][3] += a4.x * b4.w;
            acc[1][0] += a4.y * b4.x; acc[1][1] += a4.y * b4.y; acc[1][2] += a4.y * b4.z; acc[1][3] += a4.y * b4.w;
            acc[2][0] += a4.z * b4.x; acc[2][1] += a4.z * b4.y; acc[2][2] += a4.z * b4.z; acc[2][3] += a4.z * b4.w;
            acc[3][0] += a4.w * b4.x; acc[3][1] += a4.w * b4.y; acc[3][2] += a4.w * b4.z; acc[3][3] += a4.w * b4.w;
        }
        __syncthreads();
    }
    float a0 = 0.f, co = 1.f;
    if (modeE == 2) { a0 = alphap[0]; co = rsqrtf(1.f + a0 * a0); }
#pragma unroll
    for (int r = 0; r < 4; ++r) {
        int row = row0 + ty * 4 + r;
        if (modeE == 4) {
            float4 sh = ((const float4*)ang)[row];
#pragma unroll
            for (int i = 0; i < 4; ++i) {
                int col = j0 + tx * 4 + i;
                int m = col >> 1;
                float v = acc[r][i];
                if (col & 1) {
                    fvP[(size_t)row * 192 + m]       = v * sh.y;
                    fvP[(size_t)row * 192 + 64 + m]  = v * sh.z;
                    fvP[(size_t)row * 192 + 128 + m] = v * sh.w;
                } else {
                    fsP[(size_t)row * 64 + m] = v * sh.x;
                }
            }
            continue;
        }
        float cu = (modeE == 1 || modeE == 2) ? cut[row] : 0.f;
#pragma unroll
        for (int i = 0; i < 4; ++i) {
            int col = j0 + tx * 4 + i;
            float v;
            if (modeE == 1)      v = silu_f(acc[r][i]) * cu;
            else if (modeE == 2) {
                float nl = silu_f(acc[r][i]) * cu;
                v = co * oldlat[(size_t)row * 128 + col] + a0 * co * nl;
            } else if (modeE == 3) v = acc[r][i] * scale * gate[(size_t)row * 64 + col];
            else                 v = acc[r][i] * scale;
            C[(size_t)row * ldc + (size_t)col * cstride] = v;
        }
    }
}

// ================================================================ launch
extern "C" void kernel_launch(void* const* d_in, const int* in_sizes, int n_in,
                              void* d_out, int out_size, void* d_ws, size_t ws_size,
                              hipStream_t stream) {
    const float* na     = (const float*)d_in[0];
    const float* er     = (const float*)d_in[1];
    const float* ang    = (const float*)d_in[2];
    const float* len    = (const float*)d_in[3];
    const int*   ei     = (const int*)d_in[4];
    const float* W_lat0 = (const float*)d_in[5];        // 40x128
    const float* W_lat1 = (const float*)d_in[6];        // 256x128
    const float* W_fin  = (const float*)d_in[7];        // 256x64
    const float* W_env0 = (const float*)d_in[8];        // 128x320
    const float* W_env1 = (const float*)d_in[9];        // 128x192
    const float* W_q    = (const float*)d_in[10];       // 2x16x2048
    const float* W_k    = (const float*)d_in[11];       // 2x64x2048
    const float* W_evl  = (const float*)d_in[12];       // 2x2x64x64
    const float* W_prod = (const float*)d_in[13];       // 2x16x64
    const float* W_ls   = (const float*)d_in[14];       // 2x2x64x64
    const float* W_lv   = (const float*)d_in[15];       // 2x3x64x64
    const float* alpha  = (const float*)d_in[16];       // [2]
    float* out = (float*)d_out;

    const int* ctr = ei;
    const int* ngh = ei + Ee;

    // ---- workspace layout with lifetime aliasing (~161 MB total) ----
    // QWreg lower half: QWh (bf16, N*4096 = 16.7M bf16 = 8,388,608 float-slots)
    //                   ∪ sc_mp (fp32, 5,242,880)   [disjoint lifetimes]
    // QWreg upper half: fvB (fp32, 7,864,320)       [disjoint address ranges]
    float* ws = (float*)d_ws;
    float* wtsv  = ws;                       // 7,864,320  wts(192-wide) ∪ vec plane
    float* QWreg = wtsv + 7864320;           // 16,777,216
    float* sc_mp = QWreg;                    //  (alias, lower half)
    float* fvB   = QWreg + 8388608;          //  (upper half)
    float* lat   = QWreg + 16777216;         //  5,242,880
    float* lat2  = lat + 5242880;            //  5,242,880
    float* fs    = lat2 + 5242880;           //  2,621,440
    float* cut   = fs + 2621440;             //     40,960
    float* QK    = cut + 40960;              //    131,072
    float* env_s = QK + 131072;              //    262,144
    float* env_v = env_s + 262144;           //    786,432 (contiguous with env_s)
    float* es_t  = env_v + 786432;           //    262,144
    float* ev_t  = es_t + 262144;            //    786,432
    float* gateb = ev_t + 786432;            //    262,144
    float* Wlsp  = gateb + 262144;           //      8,192
    float* fvA   = out;                      //  7,864,320 in d_out (dead before final writes)

    const float rs128 = 0.08838834764831845f;   // 1/sqrt(2*M)
    const float rs192 = 0.07216878364870323f;   // 1/sqrt(3*M)

    k_cutoff<<<(Ee + 255) / 256, 256, 0, stream>>>(len, cut);
    k_qk<<<512, 256, 0, stream>>>(W_q, W_k, QK);
    k_permB<<<32, 256, 0, stream>>>(W_ls, Wlsp);
    // latent = silu(two_body @ W_lat0) * cut
    k_gemm<<<dim3(Ee / 64, 2), 256, 0, stream>>>(nullptr, 0, nullptr, ctr, ngh, na, er,
        W_lat0, 128, 40, lat, 128, 1, 1.f, cut, nullptr, nullptr, nullptr, nullptr, nullptr, nullptr, 2, 1);

    for (int l = 0; l < 2; ++l) {
        const float* latin = (l == 0) ? lat : lat2;
        k_qw<<<Nn * 4, 256, 0, stream>>>(na, QK + (size_t)l * 65536, (ushort4*)QWreg);
        k_zero<<<(Nn * 256 + 255) / 256, 256, 0, stream>>>(env_s, Nn * 256);
        if (l == 0) {
            // feat part: cols 0..127 of W_env0, fused epilogue -> fs, fvA
            k_gemm<<<dim3(Ee / 64, 2), 256, 0, stream>>>(latin, 128, nullptr, nullptr, nullptr, nullptr, nullptr,
                W_env0, 320, 128, nullptr, 0, 1, 1.f, nullptr, nullptr, nullptr, nullptr, ang, fs, fvA, 0, 4);
            // env part: cols 128..319 -> wts (192-wide)
            k_gemm<<<dim3(Ee / 64, 3), 256, 0, stream>>>(latin, 128, nullptr, nullptr, nullptr, nullptr, nullptr,
                W_env0 + 128, 320, 128, wtsv, 192, 1, 1.f, nullptr, nullptr, nullptr, nullptr, nullptr, nullptr, nullptr, 0, 0);
        } else {
            k_gemm<<<dim3(Ee / 64, 3), 256, 0, stream>>>(latin, 128, nullptr, nullptr, nullptr, nullptr, nullptr,
                W_env1, 192, 128, wtsv, 192, 1, 1.f, nullptr, nullptr, nullptr, nullptr, nullptr, nullptr, nullptr, 0, 0);
        }
        k_A2<<<Ee / 4, 256, 0, stream>>>(wtsv, ang, cut, ctr, (const ushort4*)QWreg, env_s, env_v);
        // gate_n = na @ W_prod[l]
        k_gemm<<<dim3(Nn / 64, 1), 256, 0, stream>>>(na, 16, nullptr, nullptr, nullptr, nullptr, nullptr,
            W_prod + (size_t)l * 1024, 64, 16, gateb, 64, 1, 1.f, nullptr, nullptr, nullptr, nullptr, nullptr, nullptr, nullptr, 0, 0);
        // es_t = (env_s @ W_evl[l,0]) * gate
        k_gemm<<<dim3(Nn / 64, 1), 256, 0, stream>>>(env_s, 64, nullptr, nullptr, nullptr, nullptr, nullptr,
            W_evl + (size_t)l * 8192, 64, 64, es_t, 64, 1, 1.f, nullptr, nullptr, nullptr, gateb, nullptr, nullptr, nullptr, 0, 3);
        // ev_t[:,c,:] = (env_v[:,c,:] @ W_evl[l,1]) * gate
        for (int c = 0; c < 3; ++c)
            k_gemm<<<dim3(Nn / 64, 1), 256, 0, stream>>>(env_v + c * 64, 192, nullptr, nullptr, nullptr, nullptr, nullptr,
                W_evl + (size_t)l * 8192 + 4096, 64, 64, ev_t + c * 64, 192, 1, 1.f, nullptr, nullptr, nullptr, gateb, nullptr, nullptr, nullptr, 0, 3);
        const float* fvsrc = (l == 0) ? fvA : fvB;
        k_C_s<<<Ee / 4, 256, 0, stream>>>(fs, fvsrc, es_t, ev_t, ctr, sc_mp);
        for (int c = 0; c < 3; ++c) {
            if (c == 0)      k_C_v<0><<<Ee / 4, 256, 0, stream>>>(fs, fvsrc, es_t, ev_t, ctr, wtsv);
            else if (c == 1) k_C_v<1><<<Ee / 4, 256, 0, stream>>>(fs, fvsrc, es_t, ev_t, ctr, wtsv);
            else             k_C_v<2><<<Ee / 4, 256, 0, stream>>>(fs, fvsrc, es_t, ev_t, ctr, wtsv);
            if (l == 0) {
                // feat_v[:, c-plane] -> fvB[e][c][k]
                k_gemm<<<dim3(Ee / 64, 1), 256, 0, stream>>>(wtsv, 192, nullptr, nullptr, nullptr, nullptr, nullptr,
                    W_lv, 64, 192, fvB + c * 64, 192, 1, rs192, nullptr, nullptr, nullptr, nullptr, nullptr, nullptr, nullptr, 0, 0);
            } else {
                // final feat_v -> out[:, 64 + k*3 + c]
                k_gemm<<<dim3(Ee / 64, 1), 256, 0, stream>>>(wtsv, 192, nullptr, nullptr, nullptr, nullptr, nullptr,
                    W_lv + 12288, 64, 192, out + 64 + c, 256, 3, rs192, nullptr, nullptr, nullptr, nullptr, nullptr, nullptr, nullptr, 0, 0);
            }
        }
        if (l == 0) {
            // feat_s = sc_mp @ Wls_perm / sqrt(128)   (after all k_C_v consumed old fs)
            k_gemm<<<dim3(Ee / 64, 1), 256, 0, stream>>>(sc_mp, 128, nullptr, nullptr, nullptr, nullptr, nullptr,
                Wlsp, 64, 128, fs, 64, 1, rs128, nullptr, nullptr, nullptr, nullptr, nullptr, nullptr, nullptr, 0, 0);
            // latent blend -> lat2
            k_gemm<<<dim3(Ee / 64, 2), 256, 0, stream>>>(lat, 128, sc_mp, nullptr, nullptr, nullptr, nullptr,
                W_lat1, 128, 256, lat2, 128, 1, 1.f, cut, lat, alpha, nullptr, nullptr, nullptr, nullptr, 1, 2);
        } else {
            // final feat_s = [lat2|sc] @ W_final -> out[:, 0:64]
            k_gemm<<<dim3(Ee / 64, 1), 256, 0, stream>>>(lat2, 128, sc_mp, nullptr, nullptr, nullptr, nullptr,
                W_fin, 64, 256, out, 256, 1, 1.f, nullptr, nullptr, nullptr, nullptr, nullptr, nullptr, nullptr, 1, 0);
        }
    }
    (void)in_sizes; (void)n_in; (void)out_size; (void)ws_size;
}

// Round 5
// 895.135 us; speedup vs baseline: 1.3849x; 1.3849x over previous
//
#include <hip/hip_runtime.h>

// Problem constants (fixed by the reference).
constexpr int Nn  = 4096;     // nodes
constexpr int Ee  = 40960;    // edges
constexpr int ND  = 16;       // NODE_DIM
constexpr int Mm  = 64;       // M
constexpr int HD  = 32;       // head dim

#define DI __device__ __forceinline__

DI float silu_f(float x) { return x / (1.f + __expf(-x)); }
DI unsigned short bf16r(float f) {           // round-to-nearest-even bf16
    unsigned u = __float_as_uint(f);
    return (unsigned short)((u + 0x7FFFu + ((u >> 16) & 1u)) >> 16);
}
DI float bf16f(unsigned short h) { return __uint_as_float(((unsigned)h) << 16); }

// ---------------------------------------------------------------- zero fill (graph-capture-safe)
__global__ void k_zero(float* __restrict__ p, int n) {
    int i = blockIdx.x * 256 + threadIdx.x;
    if (i < n) p[i] = 0.f;
}

// ---------------------------------------------------------------- cutoff
__global__ void k_cutoff(const float* __restrict__ len, float* __restrict__ cut) {
    int e = blockIdx.x * 256 + threadIdx.x;
    if (e >= Ee) return;
    float x  = len[e] * 0.2f;           // r / R_MAX
    float x2 = x * x, x4 = x2 * x2, x6 = x4 * x2;
    float c  = 1.f - 28.f * x6 + 48.f * x6 * x - 21.f * x4 * x4;
    cut[e] = (x < 1.f) ? c : 0.f;
}

// ---------------------------------------------------------------- QKT[l][a][g][m][j] = sum_d Wq[l,a,m*32+d]*Wk[l,mp,m*32+d]
// (mp = 4g+j; transposed layout so k_qw's reads are lane-coalesced over m)
__global__ void k_qk(const float* __restrict__ Wq, const float* __restrict__ Wk,
                     float* __restrict__ QKT) {
    int idx = blockIdx.x * 256 + threadIdx.x;      // 2*16*64*64 = 131072
    int mp = idx & 63;
    int m  = (idx >> 6) & 63;
    int a  = (idx >> 12) & 15;
    int l  = idx >> 16;
    const float* q = Wq + ((size_t)(l * ND + a)) * 2048 + m * HD;
    const float* k = Wk + ((size_t)(l * Mm + mp)) * 2048 + m * HD;
    float acc = 0.f;
#pragma unroll
    for (int d = 0; d < HD; ++d) acc += q[d] * k[d];
    // [l][a][g=mp>>2][m][j=mp&3]
    QKT[(((size_t)l * 16 + a) * 16 + (mp >> 2)) * 256 + m * 4 + (mp & 3)] = acc;
}

// ---------------------------------------------------------------- permute W_ls[0] rows: Bp[2m+p][k] = Wls[p*64+m][k]
__global__ void k_permB(const float* __restrict__ Wls, float* __restrict__ Bp) {
    int idx = blockIdx.x * 256 + threadIdx.x;      // 128*64 = 8192
    int k = idx & 63, row = idx >> 6;              // row = 2m+p
    int m = row >> 1, pp = row & 1;
    Bp[row * 64 + k] = Wls[pp * 4096 + m * 64 + k];
}

// ---------------------------------------------------------------- QWh[n][g][m] (bf16 x4 over mp) = sum_a na[n,a]*QKT[a][g][m]
// lane = m -> consecutive float4 reads: fully coalesced (1KB/wave-load)
__global__ void k_qw(const float* __restrict__ na, const float* __restrict__ QKT,
                     ushort4* __restrict__ QWh) {
    int n = blockIdx.x >> 2;
    int g = ((blockIdx.x & 3) << 2) + (threadIdx.x >> 6);
    int m = threadIdx.x & 63;
    const float4* QK4 = (const float4*)QKT;        // [a][g][m] float4-over-mp
    const float* nar = na + n * ND;
    float4 acc = {0.f, 0.f, 0.f, 0.f};
#pragma unroll
    for (int a = 0; a < ND; ++a) {
        float w = nar[a];
        float4 q = QK4[(a * 16 + g) * 64 + m];
        acc.x += w * q.x; acc.y += w * q.y; acc.z += w * q.z; acc.w += w * q.w;
    }
    ushort4 o;
    o.x = bf16r(acc.x); o.y = bf16r(acc.y); o.z = bf16r(acc.z); o.w = bf16r(acc.w);
    QWh[((size_t)n * 16 + g) * 64 + m] = o;
}

// ---------------------------------------------------------------- A2: emb, attn, env atomics (wts is 192-wide for both layers)
__global__ void k_A2(const float* __restrict__ wts, const float* __restrict__ ang,
                     const float* __restrict__ cut, const int* __restrict__ ctr,
                     const ushort4* __restrict__ QWh,
                     float* __restrict__ env_s, float* __restrict__ env_v) {
    __shared__ float xs[256];
    int wid = threadIdx.x >> 6, m = threadIdx.x & 63;
    int e = blockIdx.x * 4 + wid;
    int c = ctr[e];
    float cute = cut[e];
    float4 sh = ((const float4*)ang)[e];   // sh.x = sh0, (y,z,w) = sh1
    const float* w = wts + (size_t)e * 192;
    float2 we = ((const float2*)w)[m];     // w_env[m,0], w_env[m,1]
    float wg = w[128 + m];                 // w_gate[m]
    float es_ = we.x * sh.x;
    float ev0 = we.y * sh.y, ev1 = we.y * sh.z, ev2 = we.y * sh.w;
    xs[threadIdx.x] = es_ * wg;
    __syncthreads();
    const float4* xv = (const float4*)(xs + wid * 64);
    const ushort4* qrow = QWh + (size_t)c * 1024;    // 16 groups * 64 m
    float logit = 0.f;
#pragma unroll
    for (int g = 0; g < 16; ++g) {
        ushort4 q = qrow[g * 64 + m];
        float4 x = xv[g];
        logit += bf16f(q.x) * x.x + bf16f(q.y) * x.y + bf16f(q.z) * x.z + bf16f(q.w) * x.w;
    }
    float attn = 1.f / (1.f + __expf(-logit * 0.2f));   // sigmoid(logit/ISQRTD)
    float ga = attn * cute * 0.2f;                      // fold 1/ENV_NORM
    atomicAdd(&env_s[(size_t)c * 64 + m], es_ * ga);
    atomicAdd(&env_v[(size_t)c * 192 + m],       ev0 * ga);
    atomicAdd(&env_v[(size_t)c * 192 + 64 + m],  ev1 * ga);
    atomicAdd(&env_v[(size_t)c * 192 + 128 + m], ev2 * ga);
}

// ---------------------------------------------------------------- scalars -> sc_mp [e][2m+p]
__global__ void k_C_s(const float* __restrict__ fs, const float* __restrict__ fv,
                      const float* __restrict__ es_t, const float* __restrict__ ev_t,
                      const int* __restrict__ ctr, float* __restrict__ sc_mp) {
    int wid = threadIdx.x >> 6, m = threadIdx.x & 63;
    int e = blockIdx.x * 4 + wid;
    int c = ctr[e];
    float es  = es_t[(size_t)c * 64 + m];
    float ev0 = ev_t[(size_t)c * 192 + m];
    float ev1 = ev_t[(size_t)c * 192 + 64 + m];
    float ev2 = ev_t[(size_t)c * 192 + 128 + m];
    float f  = fs[(size_t)e * 64 + m];
    float g0 = fv[(size_t)e * 192 + m];
    float g1 = fv[(size_t)e * 192 + 64 + m];
    float g2 = fv[(size_t)e * 192 + 128 + m];
    float2 sp;
    sp.x = f * es;
    sp.y = (g0 * ev0 + g1 * ev1 + g2 * ev2) * 0.5773502691896258f;   // 1/sqrt(3)
    ((float2*)sc_mp)[(size_t)e * 64 + m] = sp;
}

// ---------------------------------------------------------------- vectors, one component plane P -> vec [e][p*64+m]
template <int P>
__global__ void k_C_v(const float* __restrict__ fs, const float* __restrict__ fv,
                      const float* __restrict__ es_t, const float* __restrict__ ev_t,
                      const int* __restrict__ ctr, float* __restrict__ vec) {
    constexpr int Pb = (P + 1) % 3, Pc = (P + 2) % 3;
    int wid = threadIdx.x >> 6, m = threadIdx.x & 63;
    int e = blockIdx.x * 4 + wid;
    int c = ctr[e];
    float es  = es_t[(size_t)c * 64 + m];
    float evP = ev_t[(size_t)c * 192 + P  * 64 + m];
    float evB = ev_t[(size_t)c * 192 + Pb * 64 + m];
    float evC = ev_t[(size_t)c * 192 + Pc * 64 + m];
    float f   = fs[(size_t)e * 64 + m];
    float gP  = fv[(size_t)e * 192 + P  * 64 + m];
    float gB  = fv[(size_t)e * 192 + Pb * 64 + m];
    float gC  = fv[(size_t)e * 192 + Pc * 64 + m];
    constexpr float is2 = 0.7071067811865475f;
    vec[(size_t)e * 192 + m]       = f * evP;                      // v1
    vec[(size_t)e * 192 + 64 + m]  = gP * es;                      // v2
    vec[(size_t)e * 192 + 128 + m] = (gB * evC - gC * evB) * is2;  // v3 (cross)
}

// ---------------------------------------------------------------- generic tiled fp32 GEMM, 64x64 tile, K-chunks of 16
// modeA: 0 = A[row*lda+k]; 1 = concat128(A|A2); 2 = two-body gather (K=40)
// modeE: 0 = C=acc*scale; 1 = silu*cut; 2 = blend latent; 3 = acc*scale*gate; 4 = l0 feat split (fs/fv)
__global__ __launch_bounds__(256) void k_gemm(
    const float* __restrict__ A, int lda, const float* __restrict__ A2,
    const int* __restrict__ ctr, const int* __restrict__ ngh,
    const float* __restrict__ naw, const float* __restrict__ er,
    const float* __restrict__ B, int ldb, int K,
    float* __restrict__ C, int ldc, int cstride, float scale,
    const float* __restrict__ cut, const float* __restrict__ oldlat,
    const float* __restrict__ alphap, const float* __restrict__ gate,
    const float* __restrict__ ang, float* __restrict__ fsP, float* __restrict__ fvP,
    int modeA, int modeE) {
    __shared__ float a_s[16][72];
    __shared__ float b_s[16][64];
    int t = threadIdx.x;
    int row0 = blockIdx.x * 64;
    int j0 = blockIdx.y * 64;
    int tx = t & 15, ty = t >> 4;
    int ar = t & 63, akq = t >> 6;
    int bj = (t & 15) * 4, bk = t >> 4;
    float acc[4][4] = {};
    int nchunks = (K + 15) >> 4;
    for (int ch = 0; ch < nchunks; ++ch) {
        int k0 = ch * 16;
        { // A tile -> a_s[k][row] (transposed)
            int row = row0 + ar;
            int k = k0 + akq * 4;
            float4 v;
            if (modeA == 0) {
                v = *(const float4*)(A + (size_t)row * lda + k);   // K multiple of 16
            } else if (modeA == 1) {
                const float* src = (k < 128) ? (A + (size_t)row * 128 + k)
                                             : (A2 + (size_t)row * 128 + (k - 128));
                v = *(const float4*)src;
            } else {
                float tmp[4];
#pragma unroll
                for (int i = 0; i < 4; ++i) {
                    int kk = k + i; float val = 0.f;
                    if (kk < 16)      val = naw[(size_t)ctr[row] * 16 + kk];
                    else if (kk < 32) val = naw[(size_t)ngh[row] * 16 + (kk - 16)];
                    else if (kk < 40) val = er[(size_t)row * 8 + (kk - 32)];
                    tmp[i] = val;
                }
                v.x = tmp[0]; v.y = tmp[1]; v.z = tmp[2]; v.w = tmp[3];
            }
            a_s[akq * 4 + 0][ar] = v.x;
            a_s[akq * 4 + 1][ar] = v.y;
            a_s[akq * 4 + 2][ar] = v.z;
            a_s[akq * 4 + 3][ar] = v.w;
        }
        { // B tile
            int k = k0 + bk;
            float4 v = {0.f, 0.f, 0.f, 0.f};
            if (k < K) v = *(const float4*)(B + (size_t)k * ldb + j0 + bj);
            *(float4*)&b_s[bk][bj] = v;
        }
        __syncthreads();
#pragma unroll
        for (int k = 0; k < 16; ++k) {
            float4 a4 = *(const float4*)&a_s[k][ty * 4];
            float4 b4 = *(const float4*)&b_s[k][tx * 4];
            acc[0][0] += a4.x * b4.x; acc[0][1] += a4.x * b4.y; acc[0][2] += a4.x * b4.z; acc[0][3] += a4.x * b4.w;
            acc[1][0] += a4.y * b4.x; acc[1][1] += a4.y * b4.y; acc[1][2] += a4.y * b4.z; acc[1][3] += a4.y * b4.w;
            acc[2][0] += a4.z * b4.x; acc[2][1] += a4.z * b4.y; acc[2][2] += a4.z * b4.z; acc[2][3] += a4.z * b4.w;
            acc[3][0] += a4.w * b4.x; acc[3][1] += a4.w * b4.y; acc[3][2] += a4.w * b4.z; acc[3][3] += a4.w * b4.w;
        }
        __syncthreads();
    }
    float a0 = 0.f, co = 1.f;
    if (modeE == 2) { a0 = alphap[0]; co = rsqrtf(1.f + a0 * a0); }
#pragma unroll
    for (int r = 0; r < 4; ++r) {
        int row = row0 + ty * 4 + r;
        if (modeE == 4) {
            float4 sh = ((const float4*)ang)[row];
#pragma unroll
            for (int i = 0; i < 4; ++i) {
                int col = j0 + tx * 4 + i;
                int m = col >> 1;
                float v = acc[r][i];
                if (col & 1) {
                    fvP[(size_t)row * 192 + m]       = v * sh.y;
                    fvP[(size_t)row * 192 + 64 + m]  = v * sh.z;
                    fvP[(size_t)row * 192 + 128 + m] = v * sh.w;
                } else {
                    fsP[(size_t)row * 64 + m] = v * sh.x;
                }
            }
            continue;
        }
        float cu = (modeE == 1 || modeE == 2) ? cut[row] : 0.f;
#pragma unroll
        for (int i = 0; i < 4; ++i) {
            int col = j0 + tx * 4 + i;
            float v;
            if (modeE == 1)      v = silu_f(acc[r][i]) * cu;
            else if (modeE == 2) {
                float nl = silu_f(acc[r][i]) * cu;
                v = co * oldlat[(size_t)row * 128 + col] + a0 * co * nl;
            } else if (modeE == 3) v = acc[r][i] * scale * gate[(size_t)row * 64 + col];
            else                 v = acc[r][i] * scale;
            C[(size_t)row * ldc + (size_t)col * cstride] = v;
        }
    }
}

// ================================================================ launch
extern "C" void kernel_launch(void* const* d_in, const int* in_sizes, int n_in,
                              void* d_out, int out_size, void* d_ws, size_t ws_size,
                              hipStream_t stream) {
    const float* na     = (const float*)d_in[0];
    const float* er     = (const float*)d_in[1];
    const float* ang    = (const float*)d_in[2];
    const float* len    = (const float*)d_in[3];
    const int*   ei     = (const int*)d_in[4];
    const float* W_lat0 = (const float*)d_in[5];        // 40x128
    const float* W_lat1 = (const float*)d_in[6];        // 256x128
    const float* W_fin  = (const float*)d_in[7];        // 256x64
    const float* W_env0 = (const float*)d_in[8];        // 128x320
    const float* W_env1 = (const float*)d_in[9];        // 128x192
    const float* W_q    = (const float*)d_in[10];       // 2x16x2048
    const float* W_k    = (const float*)d_in[11];       // 2x64x2048
    const float* W_evl  = (const float*)d_in[12];       // 2x2x64x64
    const float* W_prod = (const float*)d_in[13];       // 2x16x64
    const float* W_ls   = (const float*)d_in[14];       // 2x2x64x64
    const float* W_lv   = (const float*)d_in[15];       // 2x3x64x64
    const float* alpha  = (const float*)d_in[16];       // [2]
    float* out = (float*)d_out;

    const int* ctr = ei;
    const int* ngh = ei + Ee;

    // ---- workspace layout with lifetime aliasing (~161 MB total) ----
    float* ws = (float*)d_ws;
    float* wtsv  = ws;                       // 7,864,320  wts(192-wide) ∪ vec plane
    float* QWreg = wtsv + 7864320;           // 16,777,216
    float* sc_mp = QWreg;                    //  (alias, lower half)
    float* fvB   = QWreg + 8388608;          //  (upper half)
    float* lat   = QWreg + 16777216;         //  5,242,880
    float* lat2  = lat + 5242880;            //  5,242,880
    float* fs    = lat2 + 5242880;           //  2,621,440
    float* cut   = fs + 2621440;             //     40,960
    float* QKT   = cut + 40960;              //    131,072
    float* env_s = QKT + 131072;             //    262,144
    float* env_v = env_s + 262144;           //    786,432 (contiguous with env_s)
    float* es_t  = env_v + 786432;           //    262,144
    float* ev_t  = es_t + 262144;            //    786,432
    float* gateb = ev_t + 786432;            //    262,144
    float* Wlsp  = gateb + 262144;           //      8,192
    float* fvA   = out;                      //  7,864,320 in d_out (dead before final writes)

    const float rs128 = 0.08838834764831845f;   // 1/sqrt(2*M)
    const float rs192 = 0.07216878364870323f;   // 1/sqrt(3*M)

    k_cutoff<<<(Ee + 255) / 256, 256, 0, stream>>>(len, cut);
    k_qk<<<512, 256, 0, stream>>>(W_q, W_k, QKT);
    k_permB<<<32, 256, 0, stream>>>(W_ls, Wlsp);
    // latent = silu(two_body @ W_lat0) * cut
    k_gemm<<<dim3(Ee / 64, 2), 256, 0, stream>>>(nullptr, 0, nullptr, ctr, ngh, na, er,
        W_lat0, 128, 40, lat, 128, 1, 1.f, cut, nullptr, nullptr, nullptr, nullptr, nullptr, nullptr, 2, 1);

    for (int l = 0; l < 2; ++l) {
        const float* latin = (l == 0) ? lat : lat2;
        k_qw<<<Nn * 4, 256, 0, stream>>>(na, QKT + (size_t)l * 65536, (ushort4*)QWreg);
        k_zero<<<(Nn * 256 + 255) / 256, 256, 0, stream>>>(env_s, Nn * 256);
        if (l == 0) {
            // feat part: cols 0..127 of W_env0, fused epilogue -> fs, fvA
            k_gemm<<<dim3(Ee / 64, 2), 256, 0, stream>>>(latin, 128, nullptr, nullptr, nullptr, nullptr, nullptr,
                W_env0, 320, 128, nullptr, 0, 1, 1.f, nullptr, nullptr, nullptr, nullptr, ang, fs, fvA, 0, 4);
            // env part: cols 128..319 -> wts (192-wide)
            k_gemm<<<dim3(Ee / 64, 3), 256, 0, stream>>>(latin, 128, nullptr, nullptr, nullptr, nullptr, nullptr,
                W_env0 + 128, 320, 128, wtsv, 192, 1, 1.f, nullptr, nullptr, nullptr, nullptr, nullptr, nullptr, nullptr, 0, 0);
        } else {
            k_gemm<<<dim3(Ee / 64, 3), 256, 0, stream>>>(latin, 128, nullptr, nullptr, nullptr, nullptr, nullptr,
                W_env1, 192, 128, wtsv, 192, 1, 1.f, nullptr, nullptr, nullptr, nullptr, nullptr, nullptr, nullptr, 0, 0);
        }
        k_A2<<<Ee / 4, 256, 0, stream>>>(wtsv, ang, cut, ctr, (const ushort4*)QWreg, env_s, env_v);
        // gate_n = na @ W_prod[l]
        k_gemm<<<dim3(Nn / 64, 1), 256, 0, stream>>>(na, 16, nullptr, nullptr, nullptr, nullptr, nullptr,
            W_prod + (size_t)l * 1024, 64, 16, gateb, 64, 1, 1.f, nullptr, nullptr, nullptr, nullptr, nullptr, nullptr, nullptr, 0, 0);
        // es_t = (env_s @ W_evl[l,0]) * gate
        k_gemm<<<dim3(Nn / 64, 1), 256, 0, stream>>>(env_s, 64, nullptr, nullptr, nullptr, nullptr, nullptr,
            W_evl + (size_t)l * 8192, 64, 64, es_t, 64, 1, 1.f, nullptr, nullptr, nullptr, gateb, nullptr, nullptr, nullptr, 0, 3);
        // ev_t[:,c,:] = (env_v[:,c,:] @ W_evl[l,1]) * gate
        for (int c = 0; c < 3; ++c)
            k_gemm<<<dim3(Nn / 64, 1), 256, 0, stream>>>(env_v + c * 64, 192, nullptr, nullptr, nullptr, nullptr, nullptr,
                W_evl + (size_t)l * 8192 + 4096, 64, 64, ev_t + c * 64, 192, 1, 1.f, nullptr, nullptr, nullptr, gateb, nullptr, nullptr, nullptr, 0, 3);
        const float* fvsrc = (l == 0) ? fvA : fvB;
        k_C_s<<<Ee / 4, 256, 0, stream>>>(fs, fvsrc, es_t, ev_t, ctr, sc_mp);
        for (int c = 0; c < 3; ++c) {
            if (c == 0)      k_C_v<0><<<Ee / 4, 256, 0, stream>>>(fs, fvsrc, es_t, ev_t, ctr, wtsv);
            else if (c == 1) k_C_v<1><<<Ee / 4, 256, 0, stream>>>(fs, fvsrc, es_t, ev_t, ctr, wtsv);
            else             k_C_v<2><<<Ee / 4, 256, 0, stream>>>(fs, fvsrc, es_t, ev_t, ctr, wtsv);
            if (l == 0) {
                // feat_v[:, c-plane] -> fvB[e][c][k]
                k_gemm<<<dim3(Ee / 64, 1), 256, 0, stream>>>(wtsv, 192, nullptr, nullptr, nullptr, nullptr, nullptr,
                    W_lv, 64, 192, fvB + c * 64, 192, 1, rs192, nullptr, nullptr, nullptr, nullptr, nullptr, nullptr, nullptr, 0, 0);
            } else {
                // final feat_v -> out[:, 64 + k*3 + c]
                k_gemm<<<dim3(Ee / 64, 1), 256, 0, stream>>>(wtsv, 192, nullptr, nullptr, nullptr, nullptr, nullptr,
                    W_lv + 12288, 64, 192, out + 64 + c, 256, 3, rs192, nullptr, nullptr, nullptr, nullptr, nullptr, nullptr, nullptr, 0, 0);
            }
        }
        if (l == 0) {
            // feat_s = sc_mp @ Wls_perm / sqrt(128)   (after all k_C_v consumed old fs)
            k_gemm<<<dim3(Ee / 64, 1), 256, 0, stream>>>(sc_mp, 128, nullptr, nullptr, nullptr, nullptr, nullptr,
                Wlsp, 64, 128, fs, 64, 1, rs128, nullptr, nullptr, nullptr, nullptr, nullptr, nullptr, nullptr, 0, 0);
            // latent blend -> lat2
            k_gemm<<<dim3(Ee / 64, 2), 256, 0, stream>>>(lat, 128, sc_mp, nullptr, nullptr, nullptr, nullptr,
                W_lat1, 128, 256, lat2, 128, 1, 1.f, cut, lat, alpha, nullptr, nullptr, nullptr, nullptr, 1, 2);
        } else {
            // final feat_s = [lat2|sc] @ W_final -> out[:, 0:64]
            k_gemm<<<dim3(Ee / 64, 1), 256, 0, stream>>>(lat2, 128, sc_mp, nullptr, nullptr, nullptr, nullptr,
                W_fin, 64, 256, out, 256, 1, 1.f, nullptr, nullptr, nullptr, nullptr, nullptr, nullptr, nullptr, 1, 0);
        }
    }
    (void)in_sizes; (void)n_in; (void)out_size; (void)ws_size;
}